// Round 1
// baseline (81.094 us; speedup 1.0000x reference)
//
#include <hip/hip_runtime.h>

#define GH 32
#define GW 32
#define PITCH 34          // 32 + 2 halo (halo doubles as out-of-bounds INF)
#define NPAD (PITCH * PITCH)
#define INFV 1000000000.0f
#define EPSV 1e-6f

// One wave (64 lanes) per batch. Lane owns a 4x4 register tile:
// tr = tid>>3 (tile row 0..7), tc = tid&7 (tile col 0..7).
// In-tile Gauss-Seidel (forward + backward per sweep) gives long-range
// propagation inside the tile; cross-tile propagation is one tile ring
// (4 cells) per sweep via LDS. Single wave => no multi-wave barrier skew,
// convergence via one in-register ballot.
//
// Exactness: every update is d[v] = min(d[v], fl(w[v] + d[n])) — the same
// atomic relaxation the reference's Jacobi sweeps perform, in a different
// order. The relaxation map is monotone with a unique least fixed point in
// float32 walk-sums; the loop exits only after a certified no-change sweep
// (all 8 neighbor inequalities hold at final values), so the dist array is
// bit-identical to the reference fixed point and the backtrack path matches.

#define RELAX(i,j) {                                                          \
    const float ul = ((i)==0) ? top[(j)]   : (((j)==0) ? lft[(i)-1] : t[(i)-1][(j)-1]); \
    const float uu = ((i)==0) ? top[(j)+1] : t[(i)-1][(j)];                    \
    const float ur = ((i)==0) ? top[(j)+2] : (((j)==3) ? rgt[(i)-1] : t[(i)-1][(j)+1]); \
    const float ll = ((j)==0) ? lft[(i)]   : t[(i)][(j)-1];                    \
    const float rr = ((j)==3) ? rgt[(i)]   : t[(i)][(j)+1];                    \
    const float dl = ((i)==3) ? bot[(j)]   : (((j)==0) ? lft[(i)+1] : t[(i)+1][(j)-1]); \
    const float dd = ((i)==3) ? bot[(j)+1] : t[(i)+1][(j)];                    \
    const float dr = ((i)==3) ? bot[(j)+2] : (((j)==3) ? rgt[(i)+1] : t[(i)+1][(j)+1]); \
    const float nmin = fminf(fminf(fminf(ul, uu), fminf(ur, ll)),             \
                             fminf(fminf(rr, dl), fminf(dd, dr)));            \
    const float nd = w[i][j] + nmin;                                          \
    if (nd < t[i][j]) { t[i][j] = nd; ch = true; }                            \
}

__global__ __launch_bounds__(64)
void bbastar_kernel(const float* __restrict__ weights,
                    const int* __restrict__ source,
                    const int* __restrict__ target,
                    float* __restrict__ out) {
    __shared__ float d[NPAD];

    const int b   = blockIdx.x;
    const int tid = threadIdx.x;       // 0..63, single wave
    const int tr  = tid >> 3;          // tile row 0..7
    const int tc  = tid & 7;           // tile col 0..7
    const int r0  = tr << 2;           // global row of tile top
    const int c0  = tc << 2;           // global col of tile left
    const int base = (r0 + 1) * PITCH + (c0 + 1);   // LDS addr of tile (0,0)

    const int sr = source[2 * b];
    const int sc = source[2 * b + 1];

    // load weight tile (4x float4, 16B aligned), add EPS (matches reference)
    float w[4][4], t[4][4];
    const float* wb = weights + b * (GH * GW);
    #pragma unroll
    for (int i = 0; i < 4; ++i) {
        const float4 v = *(const float4*)(wb + (r0 + i) * GW + c0);
        w[i][0] = v.x + EPSV; w[i][1] = v.y + EPSV;
        w[i][2] = v.z + EPSV; w[i][3] = v.w + EPSV;
    }

    // zero this batch's output region (harness poisons d_out with 0xAA)
    float4* ob4 = (float4*)(out + b * (GH * GW));
    #pragma unroll
    for (int k = 0; k < 4; ++k) ob4[tid + 64 * k] = make_float4(0.f, 0.f, 0.f, 0.f);

    // init dist: INF everywhere (incl. halo = out-of-bounds INF)
    for (int i = tid; i < NPAD; i += 64) d[i] = INFV;
    #pragma unroll
    for (int i = 0; i < 4; ++i)
        #pragma unroll
        for (int j = 0; j < 4; ++j) t[i][j] = INFV;
    __syncthreads();

    // source cell = w[source] (statically-indexed writes only)
    #pragma unroll
    for (int i = 0; i < 4; ++i)
        #pragma unroll
        for (int j = 0; j < 4; ++j)
            if (sr == r0 + i && sc == c0 + j) {
                t[i][j] = w[i][j];
                d[base + i * PITCH + j] = w[i][j];
            }
    __syncthreads();

    for (int it = 0; it < 1024; ++it) {
        // ring of the 4x4 tile from LDS (neighbor tiles' previous-sweep edges)
        float top[6], bot[6], lft[4], rgt[4];
        #pragma unroll
        for (int k = 0; k < 6; ++k) {
            top[k] = d[base - PITCH - 1 + k];
            bot[k] = d[base + 4 * PITCH - 1 + k];
        }
        #pragma unroll
        for (int i = 0; i < 4; ++i) {
            lft[i] = d[base + i * PITCH - 1];
            rgt[i] = d[base + i * PITCH + 4];
        }

        bool ch = false;
        // forward in-tile Gauss-Seidel
        #pragma unroll
        for (int i = 0; i < 4; ++i)
            #pragma unroll
            for (int j = 0; j < 4; ++j) RELAX(i, j)
        // backward in-tile Gauss-Seidel
        #pragma unroll
        for (int i = 3; i >= 0; --i)
            #pragma unroll
            for (int j = 3; j >= 0; --j) RELAX(i, j)

        // publish tile (whole 4x4; keeps LDS complete for backtrack)
        #pragma unroll
        for (int i = 0; i < 4; ++i)
            #pragma unroll
            for (int j = 0; j < 4; ++j) d[base + i * PITCH + j] = t[i][j];

        const bool any = (__ballot(ch) != 0ULL);   // uniform across the wave
        __syncthreads();                           // order writes -> next reads
        if (!any) break;                           // certified fixed point
    }

    // Greedy backtrack, lane 0 only. Halo cells are exactly INFV, matching
    // the reference's where(valid, dvals, INF). Strict '<' scan in OFFS order
    // replicates jnp.argmin first-min tie-breaking.
    if (tid == 0) {
        const int drr[8] = {-1, -1, -1,  0, 0,  1, 1, 1};
        const int dcc[8] = {-1,  0,  1, -1, 1, -1, 0, 1};
        int pr = target[2 * b];
        int pc = target[2 * b + 1];
        float* ob = out + b * (GH * GW);
        for (int step = 0; step < GH * GW; ++step) {
            ob[pr * GW + pc] = 1.0f;
            if (pr == sr && pc == sc) break;
            float best = INFV;
            int bj = 0;
            #pragma unroll
            for (int j = 0; j < 8; ++j) {
                const float v = d[(pr + drr[j] + 1) * PITCH + (pc + dcc[j] + 1)];
                if (v < best) { best = v; bj = j; }
            }
            pr += drr[bj];
            pc += dcc[bj];
        }
    }
}

extern "C" void kernel_launch(void* const* d_in, const int* in_sizes, int n_in,
                              void* d_out, int out_size, void* d_ws, size_t ws_size,
                              hipStream_t stream) {
    const float* weights = (const float*)d_in[0];
    const int*   source  = (const int*)d_in[1];
    const int*   target  = (const int*)d_in[2];
    float*       out     = (float*)d_out;
    const int B = in_sizes[0] / (GH * GW);
    bbastar_kernel<<<B, 64, 0, stream>>>(weights, source, target, out);
}